// Round 2
// baseline (431.746 us; speedup 1.0000x reference)
//
#include <hip/hip_runtime.h>
#include <math.h>

// B=2048, C=1, H=W=128. Outputs (flat concat, fp32):
//   out0 target       @ float4 idx 0        : (2048,64,64)  image*mask [32:96,32:96]
//   out1 target_cut   @ float4 idx 2097152  : (2048,64,64)  min(2*image,1) crop
//   out2 target_scene @ float4 idx 4194304  : (2048,128,128) image*(mask==0)
//   out3 target_raw   @ float4 idx 12582912 : (2048,128,128) image
//
// Mask is analytic (rotated-rectangle half-plane tests) — no gather.
// NUMERICS FROZEN (round 1: absmax 0.0): fp32 ops via __f*_rn in numpy op
// order, no FMA contraction; per-image trig = fp64 cos/sin rounded to fp32.
// Round 2 change: trig moved to a prep kernel (d_ws); main kernel is one
// block per image (2048 blocks = 8/CU, single generation, no barriers),
// 16 row-chunks per thread with hoisted cos*X / -sin*X.

#define NB 2048

__global__ __launch_bounds__(256) void kd_prep(const float* __restrict__ azim,
                                               float* __restrict__ trig) {
    const int b = blockIdx.x * 256 + threadIdx.x;
    if (b < NB) {
        // a = deg2rad(-azimuth[b]) exactly as numpy: (-az) * float32(pi/180)
        const float a = __fmul_rn(-azim[b], 0.017453292519943295f);
        const double ad = (double)a;
        trig[2 * b]     = (float)cos(ad);   // correctly-rounded fp32 trig
        trig[2 * b + 1] = (float)sin(ad);
    }
}

__global__ __launch_bounds__(256) void kd_main(const float* __restrict__ image,
                                               const float* __restrict__ alpha,
                                               const float* __restrict__ trig,
                                               float* __restrict__ out) {
    const int b = blockIdx.x;           // image index, uniform per block
    const int t = threadIdx.x;          // 0..255
    const float cs = trig[2 * b];
    const float sn = trig[2 * b + 1];
    // jnp.round == round-half-even == rintf (v_rndne_f32)
    const float xu = rintf(__fadd_rn(64.0f, __fmul_rn(alpha[0], 35.0f)));
    const float xd = rintf(__fsub_rn(64.0f, __fmul_rn(alpha[1], 35.0f)));
    const float yu = rintf(__fadd_rn(64.0f, __fmul_rn(alpha[2], 35.0f)));
    const float yd = rintf(__fsub_rn(64.0f, __fmul_rn(alpha[3], 35.0f)));

    const int c4   = t & 31;            // fixed column-chunk for this thread
    const int r0   = t >> 5;            // starting row 0..7
    const int col0 = c4 << 2;
    const bool incropcol = (c4 >= 8) && (c4 < 24);

    // X columns fixed per thread -> hoist the X products (same ops, same
    // rounding as in-loop: xin = (cs*X) + (sn*Y), yin = ((-sn)*X) + (cs*Y))
    float csX[4], nsX[4];
    #pragma unroll
    for (int j = 0; j < 4; ++j) {
        const float Xf = (float)(col0 + j) - 63.5f;   // exact in fp32
        csX[j] = __fmul_rn(cs, Xf);
        nsX[j] = __fmul_rn(-sn, Xf);
    }

    const float4* __restrict__ img4 = (const float4*)image + (size_t)b * 4096;
    float4* __restrict__ out4 = (float4*)out;
    const size_t fullbase = (size_t)b * 4096;

    #pragma unroll
    for (int i = 0; i < 16; ++i) {
        const int row = r0 + (i << 3);          // rows stride 8
        const int k   = (row << 5) + c4;        // chunk index == t + 256*i
        const float4 v = img4[k];
        const float px[4] = {v.x, v.y, v.z, v.w};

        const float Yf  = (float)row - 63.5f;   // exact
        const float snY = __fmul_rn(sn, Yf);
        const float csY = __fmul_rn(cs, Yf);

        float tgt[4], scn[4];
        #pragma unroll
        for (int j = 0; j < 4; ++j) {
            const float xin  = __fadd_rn(csX[j], snY);
            const float yin  = __fadd_rn(nsX[j], csY);
            const float colf = floorf(__fadd_rn(__fadd_rn(xin, 63.5f), 0.5f));
            const float rowf = floorf(__fadd_rn(__fadd_rn(yin, 63.5f), 0.5f));
            const bool valid = (colf >= 0.0f) && (colf < 128.0f) &&
                               (rowf >= 0.0f) && (rowf < 128.0f);
            const float rc = fminf(fmaxf(rowf, 0.0f), 127.0f);
            const float cc = fminf(fmaxf(colf, 0.0f), 127.0f);
            const bool m = valid && (rc >= xd) && (rc < xu) &&
                           (cc >= yd) && (cc < yu);
            tgt[j] = m ? px[j] : 0.0f;
            scn[j] = m ? 0.0f : px[j];
        }

        out4[4194304u + fullbase + k]  =
            make_float4(scn[0], scn[1], scn[2], scn[3]);
        out4[12582912u + fullbase + k] = v;

        // crop rows 32..95 -> iterations 4..11; crop cols -> c4 in [8,24)
        if (i >= 4 && i < 12 && incropcol) {
            const size_t ti = (size_t)b * 1024 + (size_t)(row - 32) * 16
                              + (size_t)(c4 - 8);
            out4[ti] = make_float4(tgt[0], tgt[1], tgt[2], tgt[3]);
            float cut[4];
            #pragma unroll
            for (int j = 0; j < 4; ++j) {
                const float e = __fmul_rn(px[j], 2.0f);   // exact
                cut[j] = (e >= 1.0f) ? 1.0f : e;          // image_eq
            }
            out4[2097152u + ti] = make_float4(cut[0], cut[1], cut[2], cut[3]);
        }
    }
}

extern "C" void kernel_launch(void* const* d_in, const int* in_sizes, int n_in,
                              void* d_out, int out_size, void* d_ws, size_t ws_size,
                              hipStream_t stream) {
    const float* image = (const float*)d_in[0];
    const float* azim  = (const float*)d_in[1];
    const float* alpha = (const float*)d_in[2];
    float* out  = (float*)d_out;
    float* trig = (float*)d_ws;   // 2048 * 2 floats

    hipLaunchKernelGGL(kd_prep, dim3(NB / 256), dim3(256), 0, stream, azim, trig);
    hipLaunchKernelGGL(kd_main, dim3(NB), dim3(256), 0, stream,
                       image, alpha, trig, out);
}